// Round 1
// baseline (540.437 us; speedup 1.0000x reference)
//
#include <hip/hip_runtime.h>

#define NN 50000
#define NE 800000
#define INFEAT 128
#define F1 256
#define HID 64
#define CLS 40
#define NEGS 0.2f

__device__ __forceinline__ float lrelu(float x) { return x > 0.0f ? x : NEGS * x; }
__device__ __forceinline__ float sel4(float4 v, int h) {
    float r = v.x;
    if (h == 1) r = v.y;
    if (h == 2) r = v.z;
    if (h == 3) r = v.w;
    return r;
}

// ---------------- GEMM1: fea1 = x @ W1 + b1   [50000,128]x[128,256] ----------------
#define BM 64
#define BN 64
#define BK 32
__global__ __launch_bounds__(256) void gemm1_k(const float* __restrict__ A,
                                               const float* __restrict__ W,
                                               const float* __restrict__ b,
                                               float* __restrict__ out) {
    __shared__ float As[BK][BM + 4];   // transposed A tile, row stride 68 (16B aligned)
    __shared__ float Bs[BK][BN];
    int tid = threadIdx.x;
    int row0 = blockIdx.x * BM;
    int col0 = blockIdx.y * BN;
    int tx = tid & 15, ty = tid >> 4;
    float acc[4][4] = {};
    for (int k0 = 0; k0 < INFEAT; k0 += BK) {
        // A tile 64x32 -> As[k][m]
        {
            int r = tid >> 3;            // 0..31
            int c = (tid & 7) * 4;       // 0..28
            #pragma unroll
            for (int rr = r; rr < BM; rr += 32) {
                int grow = row0 + rr;
                float4 v = make_float4(0.f, 0.f, 0.f, 0.f);
                if (grow < NN) v = *(const float4*)&A[(size_t)grow * INFEAT + k0 + c];
                As[c + 0][rr] = v.x; As[c + 1][rr] = v.y;
                As[c + 2][rr] = v.z; As[c + 3][rr] = v.w;
            }
        }
        // B tile 32x64 -> Bs[k][n]
        {
            int r = tid >> 4;            // 0..15
            int c = (tid & 15) * 4;
            #pragma unroll
            for (int rr = r; rr < BK; rr += 16) {
                *(float4*)&Bs[rr][c] = *(const float4*)&W[(size_t)(k0 + rr) * F1 + col0 + c];
            }
        }
        __syncthreads();
        #pragma unroll
        for (int k = 0; k < BK; ++k) {
            float4 av = *(const float4*)&As[k][ty * 4];
            float4 bv = *(const float4*)&Bs[k][tx * 4];
            float a[4] = {av.x, av.y, av.z, av.w};
            float bb[4] = {bv.x, bv.y, bv.z, bv.w};
            #pragma unroll
            for (int i = 0; i < 4; ++i)
                #pragma unroll
                for (int j = 0; j < 4; ++j) acc[i][j] += a[i] * bb[j];
        }
        __syncthreads();
    }
    #pragma unroll
    for (int i = 0; i < 4; ++i) {
        int grow = row0 + ty * 4 + i;
        if (grow >= NN) continue;
        int gcol = col0 + tx * 4;
        float4 bv = *(const float4*)&b[gcol];
        float4 o = make_float4(acc[i][0] + bv.x, acc[i][1] + bv.y,
                               acc[i][2] + bv.z, acc[i][3] + bv.w);
        *(float4*)&out[(size_t)grow * F1 + gcol] = o;
    }
}

// ---------------- layer-1 per-node scores ----------------
__global__ void scores1_k(const float* __restrict__ fea, const float* __restrict__ att1,
                          float* __restrict__ sI, float* __restrict__ sJ) {
    int t = blockIdx.x * blockDim.x + threadIdx.x;
    if (t >= NN * 8) return;
    int n = t >> 3;
    int j = t & 7;
    int h = j >> 1, half = j & 1;
    const float4* f = (const float4*)(fea + (size_t)n * F1 + h * HID);
    const float4* a = (const float4*)(att1 + h * 2 * HID + half * HID);
    float s = 0.f;
    #pragma unroll
    for (int c = 0; c < HID / 4; ++c) {
        float4 fv = f[c], av = a[c];
        s += fv.x * av.x + fv.y * av.y + fv.z * av.z + fv.w * av.w;
    }
    if (half == 0) sI[n * 4 + h] = s;
    else           sJ[n * 4 + h] = s;
}

// ---------------- CSR build ----------------
__global__ void hist_k(const int* __restrict__ dst, int* __restrict__ deg) {
    int e = blockIdx.x * blockDim.x + threadIdx.x;
    if (e < NE) atomicAdd(&deg[dst[e]], 1);
}

__global__ __launch_bounds__(1024) void scan_k(const int* __restrict__ deg,
                                               int* __restrict__ row_off) {
    __shared__ int sums[1024];
    int tid = threadIdx.x;
    const int SEG = (NN + 1023) / 1024;  // 49
    int beg = tid * SEG;
    int end = beg + SEG; if (end > NN) end = NN;
    int s = 0;
    for (int i = beg; i < end; ++i) s += deg[i];
    sums[tid] = s;
    __syncthreads();
    for (int off = 1; off < 1024; off <<= 1) {
        int v = (tid >= off) ? sums[tid - off] : 0;
        __syncthreads();
        sums[tid] += v;
        __syncthreads();
    }
    int base = (tid > 0) ? sums[tid - 1] : 0;
    for (int i = beg; i < end; ++i) { row_off[i] = base; base += deg[i]; }
    if (beg < NN && end == NN) row_off[NN] = base;
}

__global__ void scatter_k(const int* __restrict__ src, const int* __restrict__ dst,
                          const int* __restrict__ row_off, int* __restrict__ cursor,
                          int* __restrict__ csr) {
    int e = blockIdx.x * blockDim.x + threadIdx.x;
    if (e < NE) {
        int d = dst[e];
        int pos = row_off[d] + atomicAdd(&cursor[d], 1);
        csr[pos] = src[e];
    }
}

// ---------------- layer-1 aggregation (wave per node), fused softmax+bias+relu ----------------
__global__ __launch_bounds__(256) void agg1_k(const float* __restrict__ fea,
                                              const float* __restrict__ sI,
                                              const float* __restrict__ sJ,
                                              const int* __restrict__ row_off,
                                              const int* __restrict__ csr,
                                              const float* __restrict__ bias,
                                              float* __restrict__ out) {
    int wid = threadIdx.x >> 6, lane = threadIdx.x & 63;
    int n = blockIdx.x * 4 + wid;
    if (n >= NN) return;
    float4 siv = *(const float4*)&sI[n * 4];
    float4 sjs = *(const float4*)&sJ[n * 4];
    float4 m4;
    m4.x = lrelu(siv.x + sjs.x); m4.y = lrelu(siv.y + sjs.y);
    m4.z = lrelu(siv.z + sjs.z); m4.w = lrelu(siv.w + sjs.w);
    int beg = row_off[n], end = row_off[n + 1];
    for (int e = beg + lane; e < end; e += 64) {
        int s = csr[e];
        float4 sj = *(const float4*)&sJ[s * 4];
        m4.x = fmaxf(m4.x, lrelu(siv.x + sj.x));
        m4.y = fmaxf(m4.y, lrelu(siv.y + sj.y));
        m4.z = fmaxf(m4.z, lrelu(siv.z + sj.z));
        m4.w = fmaxf(m4.w, lrelu(siv.w + sj.w));
    }
    #pragma unroll
    for (int off = 32; off; off >>= 1) {
        m4.x = fmaxf(m4.x, __shfl_xor(m4.x, off));
        m4.y = fmaxf(m4.y, __shfl_xor(m4.y, off));
        m4.z = fmaxf(m4.z, __shfl_xor(m4.z, off));
        m4.w = fmaxf(m4.w, __shfl_xor(m4.w, off));
    }
    int h = lane >> 4;
    float si = sel4(siv, h);
    float mh = sel4(m4, h);
    int c = lane * 4;
    // self loop
    float p = __expf(lrelu(si + sel4(sjs, h)) - mh);
    float asum = p;
    float4 f = *(const float4*)&fea[(size_t)n * F1 + c];
    float4 acc = make_float4(f.x * p, f.y * p, f.z * p, f.w * p);
    for (int e = beg; e < end; ++e) {
        int s = csr[e];
        float pe = __expf(lrelu(si + sJ[s * 4 + h]) - mh);
        asum += pe;
        float4 fe = *(const float4*)&fea[(size_t)s * F1 + c];
        acc.x += fe.x * pe; acc.y += fe.y * pe;
        acc.z += fe.z * pe; acc.w += fe.w * pe;
    }
    float inv = 1.0f / (asum + 1e-16f);
    float4 bv = *(const float4*)&bias[c];
    float4 o;
    o.x = fmaxf(acc.x * inv + bv.x, 0.f);
    o.y = fmaxf(acc.y * inv + bv.y, 0.f);
    o.z = fmaxf(acc.z * inv + bv.z, 0.f);
    o.w = fmaxf(acc.w * inv + bv.w, 0.f);
    *(float4*)&out[(size_t)n * F1 + c] = o;
}

// ---------------- GEMM2 (wave per node) + fused att2 scores ----------------
__global__ __launch_bounds__(256) void gemm2_k(const float* __restrict__ h1,
                                               const float* __restrict__ W2,
                                               const float* __restrict__ b2,
                                               const float* __restrict__ att2,
                                               float* __restrict__ fea2,
                                               float* __restrict__ s2I,
                                               float* __restrict__ s2J) {
    __shared__ float Ws[F1 * CLS];   // 40 KB
    __shared__ float hs[4][F1];
    int tid = threadIdx.x;
    for (int i = tid * 4; i < F1 * CLS; i += 256 * 4)
        *(float4*)&Ws[i] = *(const float4*)&W2[i];
    int wid = tid >> 6, lane = tid & 63;
    int n = blockIdx.x * 4 + wid;
    if (n < NN)
        *(float4*)&hs[wid][lane * 4] = *(const float4*)&h1[(size_t)n * F1 + lane * 4];
    __syncthreads();
    if (n >= NN) return;
    int c = lane < CLS ? lane : CLS - 1;
    float acc = b2[c];
    #pragma unroll 8
    for (int k = 0; k < F1; ++k) acc += hs[wid][k] * Ws[k * CLS + c];
    float a_i = (lane < CLS) ? att2[lane] : 0.f;
    float a_j = (lane < CLS) ? att2[CLS + lane] : 0.f;
    float si = acc * a_i, sj = acc * a_j;
    #pragma unroll
    for (int off = 32; off; off >>= 1) {
        si += __shfl_xor(si, off);
        sj += __shfl_xor(sj, off);
    }
    if (lane < CLS) fea2[(size_t)n * CLS + lane] = acc;
    if (lane == 0) { s2I[n] = si; s2J[n] = sj; }
}

// ---------------- layer-2 aggregation + bias + row softmax ----------------
__global__ __launch_bounds__(256) void agg2_k(const float* __restrict__ fea2,
                                              const float* __restrict__ s2I,
                                              const float* __restrict__ s2J,
                                              const int* __restrict__ row_off,
                                              const int* __restrict__ csr,
                                              const float* __restrict__ bias2,
                                              float* __restrict__ out) {
    int wid = threadIdx.x >> 6, lane = threadIdx.x & 63;
    int n = blockIdx.x * 4 + wid;
    if (n >= NN) return;
    float si = s2I[n], sjn = s2J[n];
    float m = lrelu(si + sjn);
    int beg = row_off[n], end = row_off[n + 1];
    for (int e = beg + lane; e < end; e += 64)
        m = fmaxf(m, lrelu(si + s2J[csr[e]]));
    #pragma unroll
    for (int off = 32; off; off >>= 1) m = fmaxf(m, __shfl_xor(m, off));
    int c = lane < CLS ? lane : 0;
    float p = __expf(lrelu(si + sjn) - m);
    float asum = p;
    float acc = fea2[(size_t)n * CLS + c] * p;
    for (int e = beg; e < end; ++e) {
        int s = csr[e];
        float pe = __expf(lrelu(si + s2J[s]) - m);
        asum += pe;
        acc += fea2[(size_t)s * CLS + c] * pe;
    }
    float row = acc / (asum + 1e-16f) + bias2[c];
    float v = (lane < CLS) ? row : -3.0e38f;
    float vm = v;
    #pragma unroll
    for (int off = 32; off; off >>= 1) vm = fmaxf(vm, __shfl_xor(vm, off));
    float ex = (lane < CLS) ? __expf(v - vm) : 0.f;
    float es = ex;
    #pragma unroll
    for (int off = 32; off; off >>= 1) es += __shfl_xor(es, off);
    if (lane < CLS) out[(size_t)n * CLS + lane] = ex / es;
}

extern "C" void kernel_launch(void* const* d_in, const int* in_sizes, int n_in,
                              void* d_out, int out_size, void* d_ws, size_t ws_size,
                              hipStream_t stream) {
    const float* x     = (const float*)d_in[0];
    const int*   ei    = (const int*)d_in[1];
    const float* w1    = (const float*)d_in[2];
    const float* b1    = (const float*)d_in[3];
    const float* att1  = (const float*)d_in[4];
    const float* bias1 = (const float*)d_in[5];
    const float* w2    = (const float*)d_in[6];
    const float* b2    = (const float*)d_in[7];
    const float* att2  = (const float*)d_in[8];
    const float* bias2 = (const float*)d_in[9];
    const int* src = ei;
    const int* dst = ei + NE;
    float* out = (float*)d_out;

    char* p = (char*)d_ws;
    auto alloc = [&](size_t bytes) {
        char* r = p;
        p += (bytes + 255) & ~(size_t)255;
        return r;
    };
    float* fea1   = (float*)alloc((size_t)NN * F1 * 4);
    float* h1     = (float*)alloc((size_t)NN * F1 * 4);
    float* sI1    = (float*)alloc((size_t)NN * 4 * 4);
    float* sJ1    = (float*)alloc((size_t)NN * 4 * 4);
    float* fea2   = (float*)alloc((size_t)NN * CLS * 4);
    float* s2I    = (float*)alloc((size_t)NN * 4);
    float* s2J    = (float*)alloc((size_t)NN * 4);
    int*   degcur = (int*)alloc((size_t)2 * NN * 4);   // deg + cursor contiguous
    int*   deg    = degcur;
    int*   cursor = degcur + NN;
    int*   row_off= (int*)alloc((size_t)(NN + 1) * 4);
    int*   csr    = (int*)alloc((size_t)NE * 4);

    hipMemsetAsync(degcur, 0, (size_t)2 * NN * 4, stream);

    dim3 g1((NN + BM - 1) / BM, F1 / BN);
    gemm1_k<<<g1, 256, 0, stream>>>(x, w1, b1, fea1);
    scores1_k<<<(NN * 8 + 255) / 256, 256, 0, stream>>>(fea1, att1, sI1, sJ1);
    hist_k<<<(NE + 255) / 256, 256, 0, stream>>>(dst, deg);
    scan_k<<<1, 1024, 0, stream>>>(deg, row_off);
    scatter_k<<<(NE + 255) / 256, 256, 0, stream>>>(src, dst, row_off, cursor, csr);
    agg1_k<<<(NN + 3) / 4, 256, 0, stream>>>(fea1, sI1, sJ1, row_off, csr, bias1, h1);
    gemm2_k<<<(NN + 3) / 4, 256, 0, stream>>>(h1, w2, b2, att2, fea2, s2I, s2J);
    agg2_k<<<(NN + 3) / 4, 256, 0, stream>>>(fea2, s2I, s2J, row_off, csr, bias2, out);
}

// Round 2
// 361.106 us; speedup vs baseline: 1.4966x; 1.4966x over previous
//
#include <hip/hip_runtime.h>
#include <hip/hip_fp16.h>

#define NN 50000
#define NE 800000
#define INFEAT 128
#define F1 256
#define HID 64
#define CLS 40
#define NEGS 0.2f

__device__ __forceinline__ float lrelu(float x) { return x > 0.0f ? x : NEGS * x; }

struct alignas(8) H4 { __half2 a, b; };

// ---------------- GEMM1: fea1h = fp16(x @ W1 + b1), fused per-node scores ----------------
#define BM 64
#define BN 64
#define BK 32
__global__ __launch_bounds__(256) void gemm1_k(const float* __restrict__ A,
                                               const float* __restrict__ W,
                                               const float* __restrict__ b,
                                               const float* __restrict__ att1,
                                               __half* __restrict__ feah,
                                               float* __restrict__ sI,
                                               float* __restrict__ sJ) {
    __shared__ float As[BK][BM + 4];
    __shared__ float Bs[BK][BN];
    int tid = threadIdx.x;
    int row0 = blockIdx.x * BM;
    int head = blockIdx.y;          // BN==HID: one head per column block
    int col0 = head * BN;
    int tx = tid & 15, ty = tid >> 4;
    float acc[4][4] = {};
    for (int k0 = 0; k0 < INFEAT; k0 += BK) {
        {
            int r = tid >> 3;
            int c = (tid & 7) * 4;
            #pragma unroll
            for (int rr = r; rr < BM; rr += 32) {
                int grow = row0 + rr;
                float4 v = make_float4(0.f, 0.f, 0.f, 0.f);
                if (grow < NN) v = *(const float4*)&A[(size_t)grow * INFEAT + k0 + c];
                As[c + 0][rr] = v.x; As[c + 1][rr] = v.y;
                As[c + 2][rr] = v.z; As[c + 3][rr] = v.w;
            }
        }
        {
            int r = tid >> 4;
            int c = (tid & 15) * 4;
            #pragma unroll
            for (int rr = r; rr < BK; rr += 16)
                *(float4*)&Bs[rr][c] = *(const float4*)&W[(size_t)(k0 + rr) * F1 + col0 + c];
        }
        __syncthreads();
        #pragma unroll
        for (int k = 0; k < BK; ++k) {
            float4 av = *(const float4*)&As[k][ty * 4];
            float4 bv = *(const float4*)&Bs[k][tx * 4];
            float a[4] = {av.x, av.y, av.z, av.w};
            float bb[4] = {bv.x, bv.y, bv.z, bv.w};
            #pragma unroll
            for (int i = 0; i < 4; ++i)
                #pragma unroll
                for (int j = 0; j < 4; ++j) acc[i][j] += a[i] * bb[j];
        }
        __syncthreads();
    }
    int gcol = col0 + tx * 4;
    float4 bv = *(const float4*)&b[gcol];
    float aI0 = att1[head * 2 * HID + tx * 4 + 0];
    float aI1 = att1[head * 2 * HID + tx * 4 + 1];
    float aI2 = att1[head * 2 * HID + tx * 4 + 2];
    float aI3 = att1[head * 2 * HID + tx * 4 + 3];
    float aJ0 = att1[head * 2 * HID + HID + tx * 4 + 0];
    float aJ1 = att1[head * 2 * HID + HID + tx * 4 + 1];
    float aJ2 = att1[head * 2 * HID + HID + tx * 4 + 2];
    float aJ3 = att1[head * 2 * HID + HID + tx * 4 + 3];
    float sIp[4], sJp[4];
    #pragma unroll
    for (int i = 0; i < 4; ++i) {
        float4 o = make_float4(acc[i][0] + bv.x, acc[i][1] + bv.y,
                               acc[i][2] + bv.z, acc[i][3] + bv.w);
        int grow = row0 + ty * 4 + i;
        if (grow < NN) {
            H4 v;
            v.a = __floats2half2_rn(o.x, o.y);
            v.b = __floats2half2_rn(o.z, o.w);
            *(H4*)&feah[(size_t)grow * F1 + gcol] = v;
        }
        sIp[i] = o.x * aI0 + o.y * aI1 + o.z * aI2 + o.w * aI3;
        sJp[i] = o.x * aJ0 + o.y * aJ1 + o.z * aJ2 + o.w * aJ3;
    }
    #pragma unroll
    for (int off = 1; off < 16; off <<= 1) {
        #pragma unroll
        for (int i = 0; i < 4; ++i) {
            sIp[i] += __shfl_xor(sIp[i], off);
            sJp[i] += __shfl_xor(sJp[i], off);
        }
    }
    if (tx == 0) {
        #pragma unroll
        for (int i = 0; i < 4; ++i) {
            int grow = row0 + ty * 4 + i;
            if (grow < NN) {
                sI[grow * 4 + head] = sIp[i];
                sJ[grow * 4 + head] = sJp[i];
            }
        }
    }
}

// ---------------- CSR build ----------------
__global__ void hist_k(const int* __restrict__ dst, int* __restrict__ deg) {
    int e = blockIdx.x * blockDim.x + threadIdx.x;
    if (e < NE) atomicAdd(&deg[dst[e]], 1);
}

__global__ __launch_bounds__(1024) void scan_k(const int* __restrict__ deg,
                                               int* __restrict__ row_off) {
    __shared__ int sums[1024];
    int tid = threadIdx.x;
    const int SEG = (NN + 1023) / 1024;
    int beg = tid * SEG;
    int end = beg + SEG; if (end > NN) end = NN;
    int s = 0;
    for (int i = beg; i < end; ++i) s += deg[i];
    sums[tid] = s;
    __syncthreads();
    for (int off = 1; off < 1024; off <<= 1) {
        int v = (tid >= off) ? sums[tid - off] : 0;
        __syncthreads();
        sums[tid] += v;
        __syncthreads();
    }
    int base = (tid > 0) ? sums[tid - 1] : 0;
    for (int i = beg; i < end; ++i) { row_off[i] = base; base += deg[i]; }
    if (beg < NN && end == NN) row_off[NN] = base;
}

__global__ void scatter_k(const int* __restrict__ src, const int* __restrict__ dst,
                          const int* __restrict__ row_off, int* __restrict__ cursor,
                          int* __restrict__ csr) {
    int e = blockIdx.x * blockDim.x + threadIdx.x;
    if (e < NE) {
        int d = dst[e];
        int pos = row_off[d] + atomicAdd(&cursor[d], 1);
        csr[pos] = src[e];
    }
}

// ---------------- layer-1 aggregation: one pass, no segment max, fp16 gathers ----------------
__global__ __launch_bounds__(256) void agg1_k(const __half* __restrict__ feah,
                                              const float* __restrict__ sI,
                                              const float* __restrict__ sJ,
                                              const int* __restrict__ row_off,
                                              const int* __restrict__ csr,
                                              const float* __restrict__ bias,
                                              float* __restrict__ out) {
    int wid = threadIdx.x >> 6, lane = threadIdx.x & 63;
    int n = blockIdx.x * 4 + wid;
    if (n >= NN) return;
    int h = lane >> 4;           // head of this lane's channels
    int c = lane * 4;            // channel group
    float si = sI[n * 4 + h];
    float sj_self = sJ[n * 4 + h];
    float p = __expf(lrelu(si + sj_self));
    float asum = p;
    H4 vs = *(const H4*)&feah[(size_t)n * F1 + c];
    float2 sx = __half22float2(vs.a), sy = __half22float2(vs.b);
    float4 acc = make_float4(sx.x * p, sx.y * p, sy.x * p, sy.y * p);
    int beg = row_off[n], end = row_off[n + 1];
    int e = beg;
    for (; e + 4 <= end; e += 4) {
        int s0 = csr[e], s1 = csr[e + 1], s2 = csr[e + 2], s3 = csr[e + 3];
        float a0 = sJ[s0 * 4 + h], a1 = sJ[s1 * 4 + h];
        float a2 = sJ[s2 * 4 + h], a3 = sJ[s3 * 4 + h];
        H4 v0 = *(const H4*)&feah[(size_t)s0 * F1 + c];
        H4 v1 = *(const H4*)&feah[(size_t)s1 * F1 + c];
        H4 v2 = *(const H4*)&feah[(size_t)s2 * F1 + c];
        H4 v3 = *(const H4*)&feah[(size_t)s3 * F1 + c];
        float p0 = __expf(lrelu(si + a0));
        float p1 = __expf(lrelu(si + a1));
        float p2 = __expf(lrelu(si + a2));
        float p3 = __expf(lrelu(si + a3));
        asum += (p0 + p1) + (p2 + p3);
        float2 x0 = __half22float2(v0.a), y0 = __half22float2(v0.b);
        float2 x1 = __half22float2(v1.a), y1 = __half22float2(v1.b);
        float2 x2 = __half22float2(v2.a), y2 = __half22float2(v2.b);
        float2 x3 = __half22float2(v3.a), y3 = __half22float2(v3.b);
        acc.x += x0.x * p0 + x1.x * p1 + x2.x * p2 + x3.x * p3;
        acc.y += x0.y * p0 + x1.y * p1 + x2.y * p2 + x3.y * p3;
        acc.z += y0.x * p0 + y1.x * p1 + y2.x * p2 + y3.x * p3;
        acc.w += y0.y * p0 + y1.y * p1 + y2.y * p2 + y3.y * p3;
    }
    for (; e < end; ++e) {
        int s = csr[e];
        float pe = __expf(lrelu(si + sJ[s * 4 + h]));
        asum += pe;
        H4 v = *(const H4*)&feah[(size_t)s * F1 + c];
        float2 x = __half22float2(v.a), y = __half22float2(v.b);
        acc.x += x.x * pe; acc.y += x.y * pe;
        acc.z += y.x * pe; acc.w += y.y * pe;
    }
    float inv = 1.0f / (asum + 1e-16f);
    float4 bv = *(const float4*)&bias[c];
    float4 o;
    o.x = fmaxf(acc.x * inv + bv.x, 0.f);
    o.y = fmaxf(acc.y * inv + bv.y, 0.f);
    o.z = fmaxf(acc.z * inv + bv.z, 0.f);
    o.w = fmaxf(acc.w * inv + bv.w, 0.f);
    *(float4*)&out[(size_t)n * F1 + c] = o;
}

// ---------------- GEMM2: thread-per-(node, 8 classes), W2 staged once ----------------
#define G2N 51   // nodes per block (255 threads = 51 * 5 groups)
__global__ __launch_bounds__(256) void gemm2_k(const float* __restrict__ h1,
                                               const float* __restrict__ W2,
                                               const float* __restrict__ b2,
                                               const float* __restrict__ att2,
                                               float* __restrict__ fea2,
                                               float* __restrict__ s2I,
                                               float* __restrict__ s2J) {
    __shared__ float Ws[F1 * CLS];         // 40 KB
    __shared__ float redI[G2N][5];
    __shared__ float redJ[G2N][5];
    int tid = threadIdx.x;
    for (int i = tid * 4; i < F1 * CLS; i += 256 * 4)
        *(float4*)&Ws[i] = *(const float4*)&W2[i];
    __syncthreads();
    int nl = tid / 5, g = tid - nl * 5;
    int n = blockIdx.x * G2N + nl;
    bool active = (tid < 255) && (n < NN);
    float acc[8];
    int c0 = g * 8;
    if (active) {
        float4 bb0 = *(const float4*)&b2[c0];
        float4 bb1 = *(const float4*)&b2[c0 + 4];
        acc[0] = bb0.x; acc[1] = bb0.y; acc[2] = bb0.z; acc[3] = bb0.w;
        acc[4] = bb1.x; acc[5] = bb1.y; acc[6] = bb1.z; acc[7] = bb1.w;
        const float* hrow = h1 + (size_t)n * F1;
        for (int k = 0; k < F1; k += 4) {
            float4 h4 = *(const float4*)&hrow[k];
            float hk[4] = {h4.x, h4.y, h4.z, h4.w};
            #pragma unroll
            for (int kk = 0; kk < 4; ++kk) {
                float4 w0 = *(const float4*)&Ws[(k + kk) * CLS + c0];
                float4 w1 = *(const float4*)&Ws[(k + kk) * CLS + c0 + 4];
                acc[0] += hk[kk] * w0.x; acc[1] += hk[kk] * w0.y;
                acc[2] += hk[kk] * w0.z; acc[3] += hk[kk] * w0.w;
                acc[4] += hk[kk] * w1.x; acc[5] += hk[kk] * w1.y;
                acc[6] += hk[kk] * w1.z; acc[7] += hk[kk] * w1.w;
            }
        }
        float sIp = 0.f, sJp = 0.f;
        #pragma unroll
        for (int j = 0; j < 8; ++j) {
            sIp += acc[j] * att2[c0 + j];
            sJp += acc[j] * att2[CLS + c0 + j];
        }
        *(float4*)&fea2[(size_t)n * CLS + c0] = make_float4(acc[0], acc[1], acc[2], acc[3]);
        *(float4*)&fea2[(size_t)n * CLS + c0 + 4] = make_float4(acc[4], acc[5], acc[6], acc[7]);
        redI[nl][g] = sIp;
        redJ[nl][g] = sJp;
    }
    __syncthreads();
    if (active && g == 0) {
        float si = redI[nl][0] + redI[nl][1] + redI[nl][2] + redI[nl][3] + redI[nl][4];
        float sj = redJ[nl][0] + redJ[nl][1] + redJ[nl][2] + redJ[nl][3] + redJ[nl][4];
        s2I[n] = si;
        s2J[n] = sj;
    }
}

// ---------------- layer-2 aggregation + bias + row softmax (one pass, no segment max) ----------------
__global__ __launch_bounds__(256) void agg2_k(const float* __restrict__ fea2,
                                              const float* __restrict__ s2I,
                                              const float* __restrict__ s2J,
                                              const int* __restrict__ row_off,
                                              const int* __restrict__ csr,
                                              const float* __restrict__ bias2,
                                              float* __restrict__ out) {
    int wid = threadIdx.x >> 6, lane = threadIdx.x & 63;
    int n = blockIdx.x * 4 + wid;
    if (n >= NN) return;
    float si = s2I[n], sjn = s2J[n];
    int c = lane < CLS ? lane : 0;
    float p = __expf(lrelu(si + sjn));
    float asum = p;
    float acc = fea2[(size_t)n * CLS + c] * p;
    int beg = row_off[n], end = row_off[n + 1];
    int e = beg;
    for (; e + 4 <= end; e += 4) {
        int s0 = csr[e], s1 = csr[e + 1], s2 = csr[e + 2], s3 = csr[e + 3];
        float p0 = __expf(lrelu(si + s2J[s0]));
        float p1 = __expf(lrelu(si + s2J[s1]));
        float p2 = __expf(lrelu(si + s2J[s2]));
        float p3 = __expf(lrelu(si + s2J[s3]));
        float f0 = fea2[(size_t)s0 * CLS + c];
        float f1 = fea2[(size_t)s1 * CLS + c];
        float f2 = fea2[(size_t)s2 * CLS + c];
        float f3 = fea2[(size_t)s3 * CLS + c];
        asum += (p0 + p1) + (p2 + p3);
        acc += f0 * p0 + f1 * p1 + f2 * p2 + f3 * p3;
    }
    for (; e < end; ++e) {
        int s = csr[e];
        float pe = __expf(lrelu(si + s2J[s]));
        asum += pe;
        acc += fea2[(size_t)s * CLS + c] * pe;
    }
    float row = acc / (asum + 1e-16f) + bias2[c];
    float v = (lane < CLS) ? row : -3.0e38f;
    float vm = v;
    #pragma unroll
    for (int off = 32; off; off >>= 1) vm = fmaxf(vm, __shfl_xor(vm, off));
    float ex = (lane < CLS) ? __expf(v - vm) : 0.f;
    float es = ex;
    #pragma unroll
    for (int off = 32; off; off >>= 1) es += __shfl_xor(es, off);
    if (lane < CLS) out[(size_t)n * CLS + lane] = ex / es;
}

extern "C" void kernel_launch(void* const* d_in, const int* in_sizes, int n_in,
                              void* d_out, int out_size, void* d_ws, size_t ws_size,
                              hipStream_t stream) {
    const float* x     = (const float*)d_in[0];
    const int*   ei    = (const int*)d_in[1];
    const float* w1    = (const float*)d_in[2];
    const float* b1    = (const float*)d_in[3];
    const float* att1  = (const float*)d_in[4];
    const float* bias1 = (const float*)d_in[5];
    const float* w2    = (const float*)d_in[6];
    const float* b2    = (const float*)d_in[7];
    const float* att2  = (const float*)d_in[8];
    const float* bias2 = (const float*)d_in[9];
    const int* src = ei;
    const int* dst = ei + NE;
    float* out = (float*)d_out;

    char* p = (char*)d_ws;
    auto alloc = [&](size_t bytes) {
        char* r = p;
        p += (bytes + 255) & ~(size_t)255;
        return r;
    };
    __half* fea1h = (__half*)alloc((size_t)NN * F1 * 2);
    float* h1     = (float*)alloc((size_t)NN * F1 * 4);
    float* sI1    = (float*)alloc((size_t)NN * 4 * 4);
    float* sJ1    = (float*)alloc((size_t)NN * 4 * 4);
    float* fea2   = (float*)alloc((size_t)NN * CLS * 4);
    float* s2I    = (float*)alloc((size_t)NN * 4);
    float* s2J    = (float*)alloc((size_t)NN * 4);
    int*   degcur = (int*)alloc((size_t)2 * NN * 4);
    int*   deg    = degcur;
    int*   cursor = degcur + NN;
    int*   row_off= (int*)alloc((size_t)(NN + 1) * 4);
    int*   csr    = (int*)alloc((size_t)NE * 4);

    hipMemsetAsync(degcur, 0, (size_t)2 * NN * 4, stream);

    dim3 g1((NN + BM - 1) / BM, F1 / BN);
    gemm1_k<<<g1, 256, 0, stream>>>(x, w1, b1, att1, fea1h, sI1, sJ1);
    hist_k<<<(NE + 255) / 256, 256, 0, stream>>>(dst, deg);
    scan_k<<<1, 1024, 0, stream>>>(deg, row_off);
    scatter_k<<<(NE + 255) / 256, 256, 0, stream>>>(src, dst, row_off, cursor, csr);
    agg1_k<<<(NN + 3) / 4, 256, 0, stream>>>(fea1h, sI1, sJ1, row_off, csr, bias1, h1);
    gemm2_k<<<(NN + G2N - 1) / G2N, 256, 0, stream>>>(h1, w2, b2, att2, fea2, s2I, s2J);
    agg2_k<<<(NN + 3) / 4, 256, 0, stream>>>(fea2, s2I, s2J, row_off, csr, bias2, out);
}

// Round 3
// 287.794 us; speedup vs baseline: 1.8779x; 1.2547x over previous
//
#include <hip/hip_runtime.h>
#include <hip/hip_fp16.h>

#define NN 50000
#define NE 800000
#define INFEAT 128
#define F1 256
#define HID 64
#define CLS 40
#define NEGS 0.2f
#define NB 49   // ceil(NN / 1024)

__device__ __forceinline__ float lrelu(float x) { return x > 0.0f ? x : NEGS * x; }

struct alignas(8) H4 { __half2 a, b; };

// ---------------- GEMM1: fea1h = fp16(x @ W1 + b1), fused per-node scores ----------------
#define BM 64
#define BN 64
#define BK 32
__global__ __launch_bounds__(256) void gemm1_k(const float* __restrict__ A,
                                               const float* __restrict__ W,
                                               const float* __restrict__ b,
                                               const float* __restrict__ att1,
                                               __half* __restrict__ feah,
                                               float* __restrict__ sI,
                                               float* __restrict__ sJ) {
    __shared__ float As[BK][BM + 4];
    __shared__ float Bs[BK][BN];
    int tid = threadIdx.x;
    int row0 = blockIdx.x * BM;
    int head = blockIdx.y;          // BN==HID: one head per column block
    int col0 = head * BN;
    int tx = tid & 15, ty = tid >> 4;
    float acc[4][4] = {};
    for (int k0 = 0; k0 < INFEAT; k0 += BK) {
        {
            int r = tid >> 3;
            int c = (tid & 7) * 4;
            #pragma unroll
            for (int rr = r; rr < BM; rr += 32) {
                int grow = row0 + rr;
                float4 v = make_float4(0.f, 0.f, 0.f, 0.f);
                if (grow < NN) v = *(const float4*)&A[(size_t)grow * INFEAT + k0 + c];
                As[c + 0][rr] = v.x; As[c + 1][rr] = v.y;
                As[c + 2][rr] = v.z; As[c + 3][rr] = v.w;
            }
        }
        {
            int r = tid >> 4;
            int c = (tid & 15) * 4;
            #pragma unroll
            for (int rr = r; rr < BK; rr += 16)
                *(float4*)&Bs[rr][c] = *(const float4*)&W[(size_t)(k0 + rr) * F1 + col0 + c];
        }
        __syncthreads();
        #pragma unroll
        for (int k = 0; k < BK; ++k) {
            float4 av = *(const float4*)&As[k][ty * 4];
            float4 bv = *(const float4*)&Bs[k][tx * 4];
            float a[4] = {av.x, av.y, av.z, av.w};
            float bb[4] = {bv.x, bv.y, bv.z, bv.w};
            #pragma unroll
            for (int i = 0; i < 4; ++i)
                #pragma unroll
                for (int j = 0; j < 4; ++j) acc[i][j] += a[i] * bb[j];
        }
        __syncthreads();
    }
    int gcol = col0 + tx * 4;
    float4 bv = *(const float4*)&b[gcol];
    float aI0 = att1[head * 2 * HID + tx * 4 + 0];
    float aI1 = att1[head * 2 * HID + tx * 4 + 1];
    float aI2 = att1[head * 2 * HID + tx * 4 + 2];
    float aI3 = att1[head * 2 * HID + tx * 4 + 3];
    float aJ0 = att1[head * 2 * HID + HID + tx * 4 + 0];
    float aJ1 = att1[head * 2 * HID + HID + tx * 4 + 1];
    float aJ2 = att1[head * 2 * HID + HID + tx * 4 + 2];
    float aJ3 = att1[head * 2 * HID + HID + tx * 4 + 3];
    float sIp[4], sJp[4];
    #pragma unroll
    for (int i = 0; i < 4; ++i) {
        float4 o = make_float4(acc[i][0] + bv.x, acc[i][1] + bv.y,
                               acc[i][2] + bv.z, acc[i][3] + bv.w);
        int grow = row0 + ty * 4 + i;
        if (grow < NN) {
            H4 v;
            v.a = __floats2half2_rn(o.x, o.y);
            v.b = __floats2half2_rn(o.z, o.w);
            *(H4*)&feah[(size_t)grow * F1 + gcol] = v;
        }
        sIp[i] = o.x * aI0 + o.y * aI1 + o.z * aI2 + o.w * aI3;
        sJp[i] = o.x * aJ0 + o.y * aJ1 + o.z * aJ2 + o.w * aJ3;
    }
    #pragma unroll
    for (int off = 1; off < 16; off <<= 1) {
        #pragma unroll
        for (int i = 0; i < 4; ++i) {
            sIp[i] += __shfl_xor(sIp[i], off);
            sJp[i] += __shfl_xor(sJp[i], off);
        }
    }
    if (tx == 0) {
        #pragma unroll
        for (int i = 0; i < 4; ++i) {
            int grow = row0 + ty * 4 + i;
            if (grow < NN) {
                sI[grow * 4 + head] = sIp[i];
                sJ[grow * 4 + head] = sJp[i];
            }
        }
    }
}

// ---------------- CSR build ----------------
__global__ void hist_k(const int* __restrict__ dst, int* __restrict__ deg) {
    int e = blockIdx.x * blockDim.x + threadIdx.x;
    if (e < NE) atomicAdd(&deg[dst[e]], 1);
}

// hierarchical scan: 49 blocks of 1024, then 1-wave scan of block sums, then add-back
__global__ __launch_bounds__(1024) void scan1_k(const int* __restrict__ deg,
                                                int* __restrict__ row_off,
                                                int* __restrict__ bsum) {
    __shared__ int tmp[1024];
    int tid = threadIdx.x;
    int gid = blockIdx.x * 1024 + tid;
    int v = (gid < NN) ? deg[gid] : 0;
    tmp[tid] = v;
    __syncthreads();
    #pragma unroll
    for (int off = 1; off < 1024; off <<= 1) {
        int t = (tid >= off) ? tmp[tid - off] : 0;
        __syncthreads();
        tmp[tid] += t;
        __syncthreads();
    }
    if (gid < NN) row_off[gid] = tmp[tid] - v;   // exclusive
    if (tid == 1023) bsum[blockIdx.x] = tmp[1023];
}

__global__ void scan2_k(const int* __restrict__ bsum, int* __restrict__ bpref) {
    int tid = threadIdx.x;           // 64 threads, one wave
    int orig = (tid < NB) ? bsum[tid] : 0;
    int v = orig;
    #pragma unroll
    for (int off = 1; off < 64; off <<= 1) {
        int t = __shfl_up(v, off);
        if (tid >= off) v += t;
    }
    if (tid < NB) bpref[tid] = v - orig;   // exclusive block prefix
}

__global__ __launch_bounds__(1024) void scan3_k(int* __restrict__ row_off,
                                                const int* __restrict__ bpref) {
    int gid = blockIdx.x * 1024 + threadIdx.x;
    if (gid < NN) row_off[gid] += bpref[blockIdx.x];
    if (gid == 0) row_off[NN] = NE;      // total degree is exactly NE
}

__global__ void scatter_k(const int* __restrict__ src, const int* __restrict__ dst,
                          const int* __restrict__ row_off, int* __restrict__ cursor,
                          int* __restrict__ csr) {
    int e = blockIdx.x * blockDim.x + threadIdx.x;
    if (e < NE) {
        int d = dst[e];
        int pos = row_off[d] + atomicAdd(&cursor[d], 1);
        csr[pos] = src[e];
    }
}

// ---------------- layer-1 aggregation: one pass, no segment max, fp16 gathers ----------------
__global__ __launch_bounds__(256) void agg1_k(const __half* __restrict__ feah,
                                              const float* __restrict__ sI,
                                              const float* __restrict__ sJ,
                                              const int* __restrict__ row_off,
                                              const int* __restrict__ csr,
                                              const float* __restrict__ bias,
                                              float* __restrict__ out) {
    int wid = threadIdx.x >> 6, lane = threadIdx.x & 63;
    int n = blockIdx.x * 4 + wid;
    if (n >= NN) return;
    int h = lane >> 4;           // head of this lane's channels
    int c = lane * 4;            // channel group
    float si = sI[n * 4 + h];
    float sj_self = sJ[n * 4 + h];
    float p = __expf(lrelu(si + sj_self));
    float asum = p;
    H4 vs = *(const H4*)&feah[(size_t)n * F1 + c];
    float2 sx = __half22float2(vs.a), sy = __half22float2(vs.b);
    float4 acc = make_float4(sx.x * p, sx.y * p, sy.x * p, sy.y * p);
    int beg = row_off[n], end = row_off[n + 1];
    int e = beg;
    for (; e + 4 <= end; e += 4) {
        int s0 = csr[e], s1 = csr[e + 1], s2 = csr[e + 2], s3 = csr[e + 3];
        float a0 = sJ[s0 * 4 + h], a1 = sJ[s1 * 4 + h];
        float a2 = sJ[s2 * 4 + h], a3 = sJ[s3 * 4 + h];
        H4 v0 = *(const H4*)&feah[(size_t)s0 * F1 + c];
        H4 v1 = *(const H4*)&feah[(size_t)s1 * F1 + c];
        H4 v2 = *(const H4*)&feah[(size_t)s2 * F1 + c];
        H4 v3 = *(const H4*)&feah[(size_t)s3 * F1 + c];
        float p0 = __expf(lrelu(si + a0));
        float p1 = __expf(lrelu(si + a1));
        float p2 = __expf(lrelu(si + a2));
        float p3 = __expf(lrelu(si + a3));
        asum += (p0 + p1) + (p2 + p3);
        float2 x0 = __half22float2(v0.a), y0 = __half22float2(v0.b);
        float2 x1 = __half22float2(v1.a), y1 = __half22float2(v1.b);
        float2 x2 = __half22float2(v2.a), y2 = __half22float2(v2.b);
        float2 x3 = __half22float2(v3.a), y3 = __half22float2(v3.b);
        acc.x += x0.x * p0 + x1.x * p1 + x2.x * p2 + x3.x * p3;
        acc.y += x0.y * p0 + x1.y * p1 + x2.y * p2 + x3.y * p3;
        acc.z += y0.x * p0 + y1.x * p1 + y2.x * p2 + y3.x * p3;
        acc.w += y0.y * p0 + y1.y * p1 + y2.y * p2 + y3.y * p3;
    }
    for (; e < end; ++e) {
        int s = csr[e];
        float pe = __expf(lrelu(si + sJ[s * 4 + h]));
        asum += pe;
        H4 v = *(const H4*)&feah[(size_t)s * F1 + c];
        float2 x = __half22float2(v.a), y = __half22float2(v.b);
        acc.x += x.x * pe; acc.y += x.y * pe;
        acc.z += y.x * pe; acc.w += y.y * pe;
    }
    float inv = 1.0f / (asum + 1e-16f);
    float4 bv = *(const float4*)&bias[c];
    float4 o;
    o.x = fmaxf(acc.x * inv + bv.x, 0.f);
    o.y = fmaxf(acc.y * inv + bv.y, 0.f);
    o.z = fmaxf(acc.z * inv + bv.z, 0.f);
    o.w = fmaxf(acc.w * inv + bv.w, 0.f);
    *(float4*)&out[(size_t)n * F1 + c] = o;
}

// ---------------- GEMM2: thread-per-(node, 8 classes), W2 staged once ----------------
#define G2N 51   // nodes per block (255 threads = 51 * 5 groups)
__global__ __launch_bounds__(256) void gemm2_k(const float* __restrict__ h1,
                                               const float* __restrict__ W2,
                                               const float* __restrict__ b2,
                                               const float* __restrict__ att2,
                                               float* __restrict__ fea2,
                                               float* __restrict__ s2I,
                                               float* __restrict__ s2J) {
    __shared__ float Ws[F1 * CLS];         // 40 KB
    __shared__ float redI[G2N][5];
    __shared__ float redJ[G2N][5];
    int tid = threadIdx.x;
    for (int i = tid * 4; i < F1 * CLS; i += 256 * 4)
        *(float4*)&Ws[i] = *(const float4*)&W2[i];
    __syncthreads();
    int nl = tid / 5, g = tid - nl * 5;
    int n = blockIdx.x * G2N + nl;
    bool active = (tid < 255) && (n < NN);
    float acc[8];
    int c0 = g * 8;
    if (active) {
        float4 bb0 = *(const float4*)&b2[c0];
        float4 bb1 = *(const float4*)&b2[c0 + 4];
        acc[0] = bb0.x; acc[1] = bb0.y; acc[2] = bb0.z; acc[3] = bb0.w;
        acc[4] = bb1.x; acc[5] = bb1.y; acc[6] = bb1.z; acc[7] = bb1.w;
        const float* hrow = h1 + (size_t)n * F1;
        for (int k = 0; k < F1; k += 4) {
            float4 h4 = *(const float4*)&hrow[k];
            float hk[4] = {h4.x, h4.y, h4.z, h4.w};
            #pragma unroll
            for (int kk = 0; kk < 4; ++kk) {
                float4 w0 = *(const float4*)&Ws[(k + kk) * CLS + c0];
                float4 w1 = *(const float4*)&Ws[(k + kk) * CLS + c0 + 4];
                acc[0] += hk[kk] * w0.x; acc[1] += hk[kk] * w0.y;
                acc[2] += hk[kk] * w0.z; acc[3] += hk[kk] * w0.w;
                acc[4] += hk[kk] * w1.x; acc[5] += hk[kk] * w1.y;
                acc[6] += hk[kk] * w1.z; acc[7] += hk[kk] * w1.w;
            }
        }
        float sIp = 0.f, sJp = 0.f;
        #pragma unroll
        for (int j = 0; j < 8; ++j) {
            sIp += acc[j] * att2[c0 + j];
            sJp += acc[j] * att2[CLS + c0 + j];
        }
        *(float4*)&fea2[(size_t)n * CLS + c0] = make_float4(acc[0], acc[1], acc[2], acc[3]);
        *(float4*)&fea2[(size_t)n * CLS + c0 + 4] = make_float4(acc[4], acc[5], acc[6], acc[7]);
        redI[nl][g] = sIp;
        redJ[nl][g] = sJp;
    }
    __syncthreads();
    if (active && g == 0) {
        float si = redI[nl][0] + redI[nl][1] + redI[nl][2] + redI[nl][3] + redI[nl][4];
        float sj = redJ[nl][0] + redJ[nl][1] + redJ[nl][2] + redJ[nl][3] + redJ[nl][4];
        s2I[n] = si;
        s2J[n] = sj;
    }
}

// ---------------- layer-2 aggregation + bias + row softmax (one pass, no segment max) ----------------
__global__ __launch_bounds__(256) void agg2_k(const float* __restrict__ fea2,
                                              const float* __restrict__ s2I,
                                              const float* __restrict__ s2J,
                                              const int* __restrict__ row_off,
                                              const int* __restrict__ csr,
                                              const float* __restrict__ bias2,
                                              float* __restrict__ out) {
    int wid = threadIdx.x >> 6, lane = threadIdx.x & 63;
    int n = blockIdx.x * 4 + wid;
    if (n >= NN) return;
    float si = s2I[n], sjn = s2J[n];
    int c = lane < CLS ? lane : 0;
    float p = __expf(lrelu(si + sjn));
    float asum = p;
    float acc = fea2[(size_t)n * CLS + c] * p;
    int beg = row_off[n], end = row_off[n + 1];
    int e = beg;
    for (; e + 4 <= end; e += 4) {
        int s0 = csr[e], s1 = csr[e + 1], s2 = csr[e + 2], s3 = csr[e + 3];
        float p0 = __expf(lrelu(si + s2J[s0]));
        float p1 = __expf(lrelu(si + s2J[s1]));
        float p2 = __expf(lrelu(si + s2J[s2]));
        float p3 = __expf(lrelu(si + s2J[s3]));
        float f0 = fea2[(size_t)s0 * CLS + c];
        float f1 = fea2[(size_t)s1 * CLS + c];
        float f2 = fea2[(size_t)s2 * CLS + c];
        float f3 = fea2[(size_t)s3 * CLS + c];
        asum += (p0 + p1) + (p2 + p3);
        acc += f0 * p0 + f1 * p1 + f2 * p2 + f3 * p3;
    }
    for (; e < end; ++e) {
        int s = csr[e];
        float pe = __expf(lrelu(si + s2J[s]));
        asum += pe;
        acc += fea2[(size_t)s * CLS + c] * pe;
    }
    float row = acc / (asum + 1e-16f) + bias2[c];
    float v = (lane < CLS) ? row : -3.0e38f;
    float vm = v;
    #pragma unroll
    for (int off = 32; off; off >>= 1) vm = fmaxf(vm, __shfl_xor(vm, off));
    float ex = (lane < CLS) ? __expf(v - vm) : 0.f;
    float es = ex;
    #pragma unroll
    for (int off = 32; off; off >>= 1) es += __shfl_xor(es, off);
    if (lane < CLS) out[(size_t)n * CLS + lane] = ex / es;
}

extern "C" void kernel_launch(void* const* d_in, const int* in_sizes, int n_in,
                              void* d_out, int out_size, void* d_ws, size_t ws_size,
                              hipStream_t stream) {
    const float* x     = (const float*)d_in[0];
    const int*   ei    = (const int*)d_in[1];
    const float* w1    = (const float*)d_in[2];
    const float* b1    = (const float*)d_in[3];
    const float* att1  = (const float*)d_in[4];
    const float* bias1 = (const float*)d_in[5];
    const float* w2    = (const float*)d_in[6];
    const float* b2    = (const float*)d_in[7];
    const float* att2  = (const float*)d_in[8];
    const float* bias2 = (const float*)d_in[9];
    const int* src = ei;
    const int* dst = ei + NE;
    float* out = (float*)d_out;

    char* p = (char*)d_ws;
    auto alloc = [&](size_t bytes) {
        char* r = p;
        p += (bytes + 255) & ~(size_t)255;
        return r;
    };
    __half* fea1h = (__half*)alloc((size_t)NN * F1 * 2);
    float* h1     = (float*)alloc((size_t)NN * F1 * 4);
    float* sI1    = (float*)alloc((size_t)NN * 4 * 4);
    float* sJ1    = (float*)alloc((size_t)NN * 4 * 4);
    float* fea2   = (float*)alloc((size_t)NN * CLS * 4);
    float* s2I    = (float*)alloc((size_t)NN * 4);
    float* s2J    = (float*)alloc((size_t)NN * 4);
    int*   degcur = (int*)alloc((size_t)2 * NN * 4);
    int*   deg    = degcur;
    int*   cursor = degcur + NN;
    int*   row_off= (int*)alloc((size_t)(NN + 1) * 4);
    int*   bsum   = (int*)alloc((size_t)NB * 4);
    int*   bpref  = (int*)alloc((size_t)NB * 4);
    int*   csr    = (int*)alloc((size_t)NE * 4);

    hipMemsetAsync(degcur, 0, (size_t)2 * NN * 4, stream);

    dim3 g1((NN + BM - 1) / BM, F1 / BN);
    gemm1_k<<<g1, 256, 0, stream>>>(x, w1, b1, att1, fea1h, sI1, sJ1);
    hist_k<<<(NE + 255) / 256, 256, 0, stream>>>(dst, deg);
    scan1_k<<<NB, 1024, 0, stream>>>(deg, row_off, bsum);
    scan2_k<<<1, 64, 0, stream>>>(bsum, bpref);
    scan3_k<<<NB, 1024, 0, stream>>>(row_off, bpref);
    scatter_k<<<(NE + 255) / 256, 256, 0, stream>>>(src, dst, row_off, cursor, csr);
    agg1_k<<<(NN + 3) / 4, 256, 0, stream>>>(fea1h, sI1, sJ1, row_off, csr, bias1, h1);
    gemm2_k<<<(NN + G2N - 1) / G2N, 256, 0, stream>>>(h1, w2, b2, att2, fea2, s2I, s2J);
    agg2_k<<<(NN + 3) / 4, 256, 0, stream>>>(fea2, s2I, s2J, row_off, csr, bias2, out);
}

// Round 4
// 282.997 us; speedup vs baseline: 1.9097x; 1.0170x over previous
//
#include <hip/hip_runtime.h>
#include <hip/hip_fp16.h>

#define NN 50000
#define NE 800000
#define INFEAT 128
#define F1 256
#define HID 64
#define CLS 40
#define NEGS 0.2f
#define NB 49   // ceil(NN / 1024)

__device__ __forceinline__ float lrelu(float x) { return x > 0.0f ? x : NEGS * x; }

struct alignas(8) H4 { __half2 a, b; };

// ---------------- GEMM1: fea1h = fp16(x @ W1 + b1), fused per-node scores ----------------
#define BM 64
#define BN 64
#define BK 32
__global__ __launch_bounds__(256) void gemm1_k(const float* __restrict__ A,
                                               const float* __restrict__ W,
                                               const float* __restrict__ b,
                                               const float* __restrict__ att1,
                                               __half* __restrict__ feah,
                                               float* __restrict__ sI,
                                               float* __restrict__ sJ) {
    __shared__ float As[BK][BM + 4];
    __shared__ float Bs[BK][BN];
    int tid = threadIdx.x;
    int row0 = blockIdx.x * BM;
    int head = blockIdx.y;          // BN==HID: one head per column block
    int col0 = head * BN;
    int tx = tid & 15, ty = tid >> 4;
    float acc[4][4] = {};
    for (int k0 = 0; k0 < INFEAT; k0 += BK) {
        {
            int r = tid >> 3;
            int c = (tid & 7) * 4;
            #pragma unroll
            for (int rr = r; rr < BM; rr += 32) {
                int grow = row0 + rr;
                float4 v = make_float4(0.f, 0.f, 0.f, 0.f);
                if (grow < NN) v = *(const float4*)&A[(size_t)grow * INFEAT + k0 + c];
                As[c + 0][rr] = v.x; As[c + 1][rr] = v.y;
                As[c + 2][rr] = v.z; As[c + 3][rr] = v.w;
            }
        }
        {
            int r = tid >> 4;
            int c = (tid & 15) * 4;
            #pragma unroll
            for (int rr = r; rr < BK; rr += 16)
                *(float4*)&Bs[rr][c] = *(const float4*)&W[(size_t)(k0 + rr) * F1 + col0 + c];
        }
        __syncthreads();
        #pragma unroll
        for (int k = 0; k < BK; ++k) {
            float4 av = *(const float4*)&As[k][ty * 4];
            float4 bv = *(const float4*)&Bs[k][tx * 4];
            float a[4] = {av.x, av.y, av.z, av.w};
            float bb[4] = {bv.x, bv.y, bv.z, bv.w};
            #pragma unroll
            for (int i = 0; i < 4; ++i)
                #pragma unroll
                for (int j = 0; j < 4; ++j) acc[i][j] += a[i] * bb[j];
        }
        __syncthreads();
    }
    int gcol = col0 + tx * 4;
    float4 bv = *(const float4*)&b[gcol];
    float aI0 = att1[head * 2 * HID + tx * 4 + 0];
    float aI1 = att1[head * 2 * HID + tx * 4 + 1];
    float aI2 = att1[head * 2 * HID + tx * 4 + 2];
    float aI3 = att1[head * 2 * HID + tx * 4 + 3];
    float aJ0 = att1[head * 2 * HID + HID + tx * 4 + 0];
    float aJ1 = att1[head * 2 * HID + HID + tx * 4 + 1];
    float aJ2 = att1[head * 2 * HID + HID + tx * 4 + 2];
    float aJ3 = att1[head * 2 * HID + HID + tx * 4 + 3];
    float sIp[4], sJp[4];
    #pragma unroll
    for (int i = 0; i < 4; ++i) {
        float4 o = make_float4(acc[i][0] + bv.x, acc[i][1] + bv.y,
                               acc[i][2] + bv.z, acc[i][3] + bv.w);
        int grow = row0 + ty * 4 + i;
        if (grow < NN) {
            H4 v;
            v.a = __floats2half2_rn(o.x, o.y);
            v.b = __floats2half2_rn(o.z, o.w);
            *(H4*)&feah[(size_t)grow * F1 + gcol] = v;
        }
        sIp[i] = o.x * aI0 + o.y * aI1 + o.z * aI2 + o.w * aI3;
        sJp[i] = o.x * aJ0 + o.y * aJ1 + o.z * aJ2 + o.w * aJ3;
    }
    #pragma unroll
    for (int off = 1; off < 16; off <<= 1) {
        #pragma unroll
        for (int i = 0; i < 4; ++i) {
            sIp[i] += __shfl_xor(sIp[i], off);
            sJp[i] += __shfl_xor(sJp[i], off);
        }
    }
    if (tx == 0) {
        #pragma unroll
        for (int i = 0; i < 4; ++i) {
            int grow = row0 + ty * 4 + i;
            if (grow < NN) {
                sI[grow * 4 + head] = sIp[i];
                sJ[grow * 4 + head] = sJp[i];
            }
        }
    }
}

// ---------------- CSR build ----------------
__global__ void hist_k(const int* __restrict__ dst, int* __restrict__ deg) {
    int e = blockIdx.x * blockDim.x + threadIdx.x;
    if (e < NE) atomicAdd(&deg[dst[e]], 1);
}

// hierarchical scan: 49 blocks of 1024, then 1-wave scan of block sums, then add-back
__global__ __launch_bounds__(1024) void scan1_k(const int* __restrict__ deg,
                                                int* __restrict__ row_off,
                                                int* __restrict__ bsum) {
    __shared__ int tmp[1024];
    int tid = threadIdx.x;
    int gid = blockIdx.x * 1024 + tid;
    int v = (gid < NN) ? deg[gid] : 0;
    tmp[tid] = v;
    __syncthreads();
    #pragma unroll
    for (int off = 1; off < 1024; off <<= 1) {
        int t = (tid >= off) ? tmp[tid - off] : 0;
        __syncthreads();
        tmp[tid] += t;
        __syncthreads();
    }
    if (gid < NN) row_off[gid] = tmp[tid] - v;   // exclusive
    if (tid == 1023) bsum[blockIdx.x] = tmp[1023];
}

__global__ void scan2_k(const int* __restrict__ bsum, int* __restrict__ bpref) {
    int tid = threadIdx.x;           // 64 threads, one wave
    int orig = (tid < NB) ? bsum[tid] : 0;
    int v = orig;
    #pragma unroll
    for (int off = 1; off < 64; off <<= 1) {
        int t = __shfl_up(v, off);
        if (tid >= off) v += t;
    }
    if (tid < NB) bpref[tid] = v - orig;   // exclusive block prefix
}

__global__ __launch_bounds__(1024) void scan3_k(int* __restrict__ row_off,
                                                const int* __restrict__ bpref) {
    int gid = blockIdx.x * 1024 + threadIdx.x;
    if (gid < NN) row_off[gid] += bpref[blockIdx.x];
    if (gid == 0) row_off[NN] = NE;      // total degree is exactly NE
}

__global__ void scatter_k(const int* __restrict__ src, const int* __restrict__ dst,
                          const int* __restrict__ row_off, int* __restrict__ cursor,
                          int* __restrict__ csr) {
    int e = blockIdx.x * blockDim.x + threadIdx.x;
    if (e < NE) {
        int d = dst[e];
        int pos = row_off[d] + atomicAdd(&cursor[d], 1);
        csr[pos] = src[e];
    }
}

// ---------------- layer-1 aggregation: one pass, no segment max, fp16 gathers, 8-deep ----------------
__global__ __launch_bounds__(256) void agg1_k(const __half* __restrict__ feah,
                                              const float* __restrict__ sI,
                                              const float* __restrict__ sJ,
                                              const int* __restrict__ row_off,
                                              const int* __restrict__ csr,
                                              const float* __restrict__ bias,
                                              float* __restrict__ out) {
    int wid = threadIdx.x >> 6, lane = threadIdx.x & 63;
    int n = blockIdx.x * 4 + wid;
    if (n >= NN) return;
    int h = lane >> 4;           // head of this lane's channels
    int c = lane * 4;            // channel group
    float si = sI[n * 4 + h];
    float sj_self = sJ[n * 4 + h];
    float p = __expf(lrelu(si + sj_self));
    float asum = p;
    H4 vs = *(const H4*)&feah[(size_t)n * F1 + c];
    float2 sx = __half22float2(vs.a), sy = __half22float2(vs.b);
    float4 acc = make_float4(sx.x * p, sx.y * p, sy.x * p, sy.y * p);
    int beg = row_off[n], end = row_off[n + 1];
    int e = beg;
    for (; e + 8 <= end; e += 8) {
        int s0 = csr[e + 0], s1 = csr[e + 1], s2 = csr[e + 2], s3 = csr[e + 3];
        int s4 = csr[e + 4], s5 = csr[e + 5], s6 = csr[e + 6], s7 = csr[e + 7];
        float a0 = sJ[s0 * 4 + h], a1 = sJ[s1 * 4 + h];
        float a2 = sJ[s2 * 4 + h], a3 = sJ[s3 * 4 + h];
        float a4 = sJ[s4 * 4 + h], a5 = sJ[s5 * 4 + h];
        float a6 = sJ[s6 * 4 + h], a7 = sJ[s7 * 4 + h];
        H4 v0 = *(const H4*)&feah[(size_t)s0 * F1 + c];
        H4 v1 = *(const H4*)&feah[(size_t)s1 * F1 + c];
        H4 v2 = *(const H4*)&feah[(size_t)s2 * F1 + c];
        H4 v3 = *(const H4*)&feah[(size_t)s3 * F1 + c];
        H4 v4 = *(const H4*)&feah[(size_t)s4 * F1 + c];
        H4 v5 = *(const H4*)&feah[(size_t)s5 * F1 + c];
        H4 v6 = *(const H4*)&feah[(size_t)s6 * F1 + c];
        H4 v7 = *(const H4*)&feah[(size_t)s7 * F1 + c];
        float p0 = __expf(lrelu(si + a0));
        float p1 = __expf(lrelu(si + a1));
        float p2 = __expf(lrelu(si + a2));
        float p3 = __expf(lrelu(si + a3));
        float p4 = __expf(lrelu(si + a4));
        float p5 = __expf(lrelu(si + a5));
        float p6 = __expf(lrelu(si + a6));
        float p7 = __expf(lrelu(si + a7));
        asum += ((p0 + p1) + (p2 + p3)) + ((p4 + p5) + (p6 + p7));
        float2 x0 = __half22float2(v0.a), y0 = __half22float2(v0.b);
        float2 x1 = __half22float2(v1.a), y1 = __half22float2(v1.b);
        float2 x2 = __half22float2(v2.a), y2 = __half22float2(v2.b);
        float2 x3 = __half22float2(v3.a), y3 = __half22float2(v3.b);
        float2 x4 = __half22float2(v4.a), y4 = __half22float2(v4.b);
        float2 x5 = __half22float2(v5.a), y5 = __half22float2(v5.b);
        float2 x6 = __half22float2(v6.a), y6 = __half22float2(v6.b);
        float2 x7 = __half22float2(v7.a), y7 = __half22float2(v7.b);
        acc.x += (x0.x * p0 + x1.x * p1 + x2.x * p2 + x3.x * p3)
               + (x4.x * p4 + x5.x * p5 + x6.x * p6 + x7.x * p7);
        acc.y += (x0.y * p0 + x1.y * p1 + x2.y * p2 + x3.y * p3)
               + (x4.y * p4 + x5.y * p5 + x6.y * p6 + x7.y * p7);
        acc.z += (y0.x * p0 + y1.x * p1 + y2.x * p2 + y3.x * p3)
               + (y4.x * p4 + y5.x * p5 + y6.x * p6 + y7.x * p7);
        acc.w += (y0.y * p0 + y1.y * p1 + y2.y * p2 + y3.y * p3)
               + (y4.y * p4 + y5.y * p5 + y6.y * p6 + y7.y * p7);
    }
    for (; e + 4 <= end; e += 4) {
        int s0 = csr[e], s1 = csr[e + 1], s2 = csr[e + 2], s3 = csr[e + 3];
        float a0 = sJ[s0 * 4 + h], a1 = sJ[s1 * 4 + h];
        float a2 = sJ[s2 * 4 + h], a3 = sJ[s3 * 4 + h];
        H4 v0 = *(const H4*)&feah[(size_t)s0 * F1 + c];
        H4 v1 = *(const H4*)&feah[(size_t)s1 * F1 + c];
        H4 v2 = *(const H4*)&feah[(size_t)s2 * F1 + c];
        H4 v3 = *(const H4*)&feah[(size_t)s3 * F1 + c];
        float p0 = __expf(lrelu(si + a0));
        float p1 = __expf(lrelu(si + a1));
        float p2 = __expf(lrelu(si + a2));
        float p3 = __expf(lrelu(si + a3));
        asum += (p0 + p1) + (p2 + p3);
        float2 x0 = __half22float2(v0.a), y0 = __half22float2(v0.b);
        float2 x1 = __half22float2(v1.a), y1 = __half22float2(v1.b);
        float2 x2 = __half22float2(v2.a), y2 = __half22float2(v2.b);
        float2 x3 = __half22float2(v3.a), y3 = __half22float2(v3.b);
        acc.x += x0.x * p0 + x1.x * p1 + x2.x * p2 + x3.x * p3;
        acc.y += x0.y * p0 + x1.y * p1 + x2.y * p2 + x3.y * p3;
        acc.z += y0.x * p0 + y1.x * p1 + y2.x * p2 + y3.x * p3;
        acc.w += y0.y * p0 + y1.y * p1 + y2.y * p2 + y3.y * p3;
    }
    for (; e < end; ++e) {
        int s = csr[e];
        float pe = __expf(lrelu(si + sJ[s * 4 + h]));
        asum += pe;
        H4 v = *(const H4*)&feah[(size_t)s * F1 + c];
        float2 x = __half22float2(v.a), y = __half22float2(v.b);
        acc.x += x.x * pe; acc.y += x.y * pe;
        acc.z += y.x * pe; acc.w += y.y * pe;
    }
    float inv = 1.0f / (asum + 1e-16f);
    float4 bv = *(const float4*)&bias[c];
    float4 o;
    o.x = fmaxf(acc.x * inv + bv.x, 0.f);
    o.y = fmaxf(acc.y * inv + bv.y, 0.f);
    o.z = fmaxf(acc.z * inv + bv.z, 0.f);
    o.w = fmaxf(acc.w * inv + bv.w, 0.f);
    *(float4*)&out[(size_t)n * F1 + c] = o;
}

// ---------------- GEMM2: thread-per-(node, 8 classes), W2 staged once ----------------
#define G2N 51   // nodes per block (255 threads = 51 * 5 groups)
__global__ __launch_bounds__(256) void gemm2_k(const float* __restrict__ h1,
                                               const float* __restrict__ W2,
                                               const float* __restrict__ b2,
                                               const float* __restrict__ att2,
                                               float* __restrict__ fea2,
                                               float* __restrict__ s2I,
                                               float* __restrict__ s2J) {
    __shared__ float Ws[F1 * CLS];         // 40 KB
    __shared__ float redI[G2N][5];
    __shared__ float redJ[G2N][5];
    int tid = threadIdx.x;
    for (int i = tid * 4; i < F1 * CLS; i += 256 * 4)
        *(float4*)&Ws[i] = *(const float4*)&W2[i];
    __syncthreads();
    int nl = tid / 5, g = tid - nl * 5;
    int n = blockIdx.x * G2N + nl;
    bool active = (tid < 255) && (n < NN);
    float acc[8];
    int c0 = g * 8;
    if (active) {
        float4 bb0 = *(const float4*)&b2[c0];
        float4 bb1 = *(const float4*)&b2[c0 + 4];
        acc[0] = bb0.x; acc[1] = bb0.y; acc[2] = bb0.z; acc[3] = bb0.w;
        acc[4] = bb1.x; acc[5] = bb1.y; acc[6] = bb1.z; acc[7] = bb1.w;
        const float* hrow = h1 + (size_t)n * F1;
        for (int k = 0; k < F1; k += 4) {
            float4 h4 = *(const float4*)&hrow[k];
            float hk[4] = {h4.x, h4.y, h4.z, h4.w};
            #pragma unroll
            for (int kk = 0; kk < 4; ++kk) {
                float4 w0 = *(const float4*)&Ws[(k + kk) * CLS + c0];
                float4 w1 = *(const float4*)&Ws[(k + kk) * CLS + c0 + 4];
                acc[0] += hk[kk] * w0.x; acc[1] += hk[kk] * w0.y;
                acc[2] += hk[kk] * w0.z; acc[3] += hk[kk] * w0.w;
                acc[4] += hk[kk] * w1.x; acc[5] += hk[kk] * w1.y;
                acc[6] += hk[kk] * w1.z; acc[7] += hk[kk] * w1.w;
            }
        }
        float sIp = 0.f, sJp = 0.f;
        #pragma unroll
        for (int j = 0; j < 8; ++j) {
            sIp += acc[j] * att2[c0 + j];
            sJp += acc[j] * att2[CLS + c0 + j];
        }
        *(float4*)&fea2[(size_t)n * CLS + c0] = make_float4(acc[0], acc[1], acc[2], acc[3]);
        *(float4*)&fea2[(size_t)n * CLS + c0 + 4] = make_float4(acc[4], acc[5], acc[6], acc[7]);
        redI[nl][g] = sIp;
        redJ[nl][g] = sJp;
    }
    __syncthreads();
    if (active && g == 0) {
        float si = redI[nl][0] + redI[nl][1] + redI[nl][2] + redI[nl][3] + redI[nl][4];
        float sj = redJ[nl][0] + redJ[nl][1] + redJ[nl][2] + redJ[nl][3] + redJ[nl][4];
        s2I[n] = si;
        s2J[n] = sj;
    }
}

// ---------------- layer-2 aggregation + bias + row softmax (one pass, 8-deep) ----------------
__global__ __launch_bounds__(256) void agg2_k(const float* __restrict__ fea2,
                                              const float* __restrict__ s2I,
                                              const float* __restrict__ s2J,
                                              const int* __restrict__ row_off,
                                              const int* __restrict__ csr,
                                              const float* __restrict__ bias2,
                                              float* __restrict__ out) {
    int wid = threadIdx.x >> 6, lane = threadIdx.x & 63;
    int n = blockIdx.x * 4 + wid;
    if (n >= NN) return;
    float si = s2I[n], sjn = s2J[n];
    int c = lane < CLS ? lane : 0;
    float p = __expf(lrelu(si + sjn));
    float asum = p;
    float acc = fea2[(size_t)n * CLS + c] * p;
    int beg = row_off[n], end = row_off[n + 1];
    int e = beg;
    for (; e + 8 <= end; e += 8) {
        int s0 = csr[e + 0], s1 = csr[e + 1], s2 = csr[e + 2], s3 = csr[e + 3];
        int s4 = csr[e + 4], s5 = csr[e + 5], s6 = csr[e + 6], s7 = csr[e + 7];
        float a0 = s2J[s0], a1 = s2J[s1], a2 = s2J[s2], a3 = s2J[s3];
        float a4 = s2J[s4], a5 = s2J[s5], a6 = s2J[s6], a7 = s2J[s7];
        float f0 = fea2[(size_t)s0 * CLS + c];
        float f1 = fea2[(size_t)s1 * CLS + c];
        float f2 = fea2[(size_t)s2 * CLS + c];
        float f3 = fea2[(size_t)s3 * CLS + c];
        float f4 = fea2[(size_t)s4 * CLS + c];
        float f5 = fea2[(size_t)s5 * CLS + c];
        float f6 = fea2[(size_t)s6 * CLS + c];
        float f7 = fea2[(size_t)s7 * CLS + c];
        float p0 = __expf(lrelu(si + a0));
        float p1 = __expf(lrelu(si + a1));
        float p2 = __expf(lrelu(si + a2));
        float p3 = __expf(lrelu(si + a3));
        float p4 = __expf(lrelu(si + a4));
        float p5 = __expf(lrelu(si + a5));
        float p6 = __expf(lrelu(si + a6));
        float p7 = __expf(lrelu(si + a7));
        asum += ((p0 + p1) + (p2 + p3)) + ((p4 + p5) + (p6 + p7));
        acc += (f0 * p0 + f1 * p1 + f2 * p2 + f3 * p3)
             + (f4 * p4 + f5 * p5 + f6 * p6 + f7 * p7);
    }
    for (; e + 4 <= end; e += 4) {
        int s0 = csr[e], s1 = csr[e + 1], s2 = csr[e + 2], s3 = csr[e + 3];
        float p0 = __expf(lrelu(si + s2J[s0]));
        float p1 = __expf(lrelu(si + s2J[s1]));
        float p2 = __expf(lrelu(si + s2J[s2]));
        float p3 = __expf(lrelu(si + s2J[s3]));
        float f0 = fea2[(size_t)s0 * CLS + c];
        float f1 = fea2[(size_t)s1 * CLS + c];
        float f2 = fea2[(size_t)s2 * CLS + c];
        float f3 = fea2[(size_t)s3 * CLS + c];
        asum += (p0 + p1) + (p2 + p3);
        acc += f0 * p0 + f1 * p1 + f2 * p2 + f3 * p3;
    }
    for (; e < end; ++e) {
        int s = csr[e];
        float pe = __expf(lrelu(si + s2J[s]));
        asum += pe;
        acc += fea2[(size_t)s * CLS + c] * pe;
    }
    float row = acc / (asum + 1e-16f) + bias2[c];
    float v = (lane < CLS) ? row : -3.0e38f;
    float vm = v;
    #pragma unroll
    for (int off = 32; off; off >>= 1) vm = fmaxf(vm, __shfl_xor(vm, off));
    float ex = (lane < CLS) ? __expf(v - vm) : 0.f;
    float es = ex;
    #pragma unroll
    for (int off = 32; off; off >>= 1) es += __shfl_xor(es, off);
    if (lane < CLS) out[(size_t)n * CLS + lane] = ex / es;
}

extern "C" void kernel_launch(void* const* d_in, const int* in_sizes, int n_in,
                              void* d_out, int out_size, void* d_ws, size_t ws_size,
                              hipStream_t stream) {
    const float* x     = (const float*)d_in[0];
    const int*   ei    = (const int*)d_in[1];
    const float* w1    = (const float*)d_in[2];
    const float* b1    = (const float*)d_in[3];
    const float* att1  = (const float*)d_in[4];
    const float* bias1 = (const float*)d_in[5];
    const float* w2    = (const float*)d_in[6];
    const float* b2    = (const float*)d_in[7];
    const float* att2  = (const float*)d_in[8];
    const float* bias2 = (const float*)d_in[9];
    const int* src = ei;
    const int* dst = ei + NE;
    float* out = (float*)d_out;

    char* p = (char*)d_ws;
    auto alloc = [&](size_t bytes) {
        char* r = p;
        p += (bytes + 255) & ~(size_t)255;
        return r;
    };
    __half* fea1h = (__half*)alloc((size_t)NN * F1 * 2);
    float* h1     = (float*)alloc((size_t)NN * F1 * 4);
    float* sI1    = (float*)alloc((size_t)NN * 4 * 4);
    float* sJ1    = (float*)alloc((size_t)NN * 4 * 4);
    float* fea2   = (float*)alloc((size_t)NN * CLS * 4);
    float* s2I    = (float*)alloc((size_t)NN * 4);
    float* s2J    = (float*)alloc((size_t)NN * 4);
    int*   degcur = (int*)alloc((size_t)2 * NN * 4);
    int*   deg    = degcur;
    int*   cursor = degcur + NN;
    int*   row_off= (int*)alloc((size_t)(NN + 1) * 4);
    int*   bsum   = (int*)alloc((size_t)NB * 4);
    int*   bpref  = (int*)alloc((size_t)NB * 4);
    int*   csr    = (int*)alloc((size_t)NE * 4);

    hipMemsetAsync(degcur, 0, (size_t)2 * NN * 4, stream);

    dim3 g1((NN + BM - 1) / BM, F1 / BN);
    gemm1_k<<<g1, 256, 0, stream>>>(x, w1, b1, att1, fea1h, sI1, sJ1);
    hist_k<<<(NE + 255) / 256, 256, 0, stream>>>(dst, deg);
    scan1_k<<<NB, 1024, 0, stream>>>(deg, row_off, bsum);
    scan2_k<<<1, 64, 0, stream>>>(bsum, bpref);
    scan3_k<<<NB, 1024, 0, stream>>>(row_off, bpref);
    scatter_k<<<(NE + 255) / 256, 256, 0, stream>>>(src, dst, row_off, cursor, csr);
    agg1_k<<<(NN + 3) / 4, 256, 0, stream>>>(fea1h, sI1, sJ1, row_off, csr, bias1, h1);
    gemm2_k<<<(NN + G2N - 1) / G2N, 256, 0, stream>>>(h1, w2, b2, att2, fea2, s2I, s2J);
    agg2_k<<<(NN + 3) / 4, 256, 0, stream>>>(fea2, s2I, s2J, row_off, csr, bias2, out);
}